// Round 1
// baseline (16312.250 us; speedup 1.0000x reference)
//
#include <hip/hip_runtime.h>
#include <math.h>

#define VSZ 50000
#define OOVN 50
#define VE 50050
#define EMB 256
#define HE 512
#define HD 512
#define NB 32
#define SRC 400
#define TDD 30
#define G3 1536   // 3*HE = 3*HD

__device__ __forceinline__ float sigmf(float x) { return 1.f / (1.f + expf(-x)); }

// out[c*rows + r] = in[r*cols + c]
__global__ __launch_bounds__(256) void transpose_kernel(const float* __restrict__ in,
                                                        float* __restrict__ out,
                                                        int rows, int cols) {
    int idx = blockIdx.x * 256 + threadIdx.x;
    if (idx >= rows * cols) return;
    int r = idx / cols, c = idx % cols;
    out[c * rows + r] = in[idx];
}

// gi[(s*NB+n)*G3 + c] = bih[c] + sum_e embed[ids[n*steps+s]][e] * WihT[e*G3+c]
// block: 16 rows (flat row = s*NB+n), 256 cols (blockIdx.y chunk)
__global__ __launch_bounds__(256) void gi_kernel(const int* __restrict__ ids,
                                                 const float* __restrict__ embed,
                                                 const float* __restrict__ WihT,
                                                 const float* __restrict__ bih,
                                                 float* __restrict__ gi, int steps) {
    __shared__ float sx[16][EMB];
    __shared__ int stok[16];
    int tid = threadIdx.x;
    int g0 = blockIdx.x * 16;
    if (tid < 16) {
        int row = g0 + tid;
        int s = row / NB, n = row % NB;
        stok[tid] = ids[n * steps + s];
    }
    __syncthreads();
    for (int r = 0; r < 16; ++r) sx[r][tid] = embed[(size_t)stok[r] * EMB + tid];
    __syncthreads();
    int c = blockIdx.y * 256 + tid;
    float b = bih[c];
    float acc[16];
#pragma unroll
    for (int r = 0; r < 16; ++r) acc[r] = b;
    for (int e = 0; e < EMB; e += 4) {
        float w0 = WihT[(size_t)(e + 0) * G3 + c];
        float w1 = WihT[(size_t)(e + 1) * G3 + c];
        float w2 = WihT[(size_t)(e + 2) * G3 + c];
        float w3 = WihT[(size_t)(e + 3) * G3 + c];
#pragma unroll
        for (int r = 0; r < 16; ++r) {
            float4 x4 = *(const float4*)&sx[r][e];
            acc[r] += x4.x * w0 + x4.y * w1 + x4.z * w2 + x4.w * w3;
        }
    }
#pragma unroll
    for (int r = 0; r < 16; ++r) gi[(size_t)(g0 + r) * G3 + c] = acc[r];
}

// One encoder scan step, both directions (blockIdx.z). block 256 = 8n x 32j.
// grid (16 jchunks, 4 ngroups, 2 dirs)
__global__ __launch_bounds__(256) void enc_step_kernel(
    const float* __restrict__ giF, const float* __restrict__ giB,
    const float* __restrict__ WhhTf, const float* __restrict__ WhhTb,
    const float* __restrict__ bhhf, const float* __restrict__ bhhb,
    const float* __restrict__ hFi, float* __restrict__ hFo,
    const float* __restrict__ hBi, float* __restrict__ hBo,
    float* __restrict__ enc, int t) {
    int z = blockIdx.z;
    const float* gi   = z ? giB : giF;
    const float* WhhT = z ? WhhTb : WhhTf;
    const float* bhh  = z ? bhhb : bhhf;
    const float* hin  = z ? hBi : hFi;
    float* hout       = z ? hBo : hFo;
    int s = z ? (SRC - 1 - t) : t;

    __shared__ float sh[8][HE];
    int tid = threadIdx.x;
    int n0 = blockIdx.y * 8;
    for (int i = tid; i < 8 * HE; i += 256)
        sh[i >> 9][i & 511] = hin[(size_t)(n0 + (i >> 9)) * HE + (i & 511)];
    __syncthreads();

    int j = blockIdx.x * 32 + (tid & 31);
    int nl = tid >> 5;
    int n = n0 + nl;
    float aR = bhh[j], aZ = bhh[HE + j], aN = bhh[2 * HE + j];
    for (int k = 0; k < HE; k += 4) {
        float4 h4 = *(const float4*)&sh[nl][k];
        const float* w0 = WhhT + (size_t)(k + 0) * G3;
        const float* w1 = WhhT + (size_t)(k + 1) * G3;
        const float* w2 = WhhT + (size_t)(k + 2) * G3;
        const float* w3 = WhhT + (size_t)(k + 3) * G3;
        aR += h4.x * w0[j] + h4.y * w1[j] + h4.z * w2[j] + h4.w * w3[j];
        aZ += h4.x * w0[HE + j] + h4.y * w1[HE + j] + h4.z * w2[HE + j] + h4.w * w3[HE + j];
        aN += h4.x * w0[2 * HE + j] + h4.y * w1[2 * HE + j] + h4.z * w2[2 * HE + j] + h4.w * w3[2 * HE + j];
    }
    const float* gir = gi + (size_t)(s * NB + n) * G3;
    float r  = sigmf(gir[j] + aR);
    float zz = sigmf(gir[HE + j] + aZ);
    float nn = tanhf(gir[2 * HE + j] + r * aN);
    float hp = sh[nl][j];
    float h = (1.f - zz) * nn + zz * hp;
    hout[(size_t)n * HE + j] = h;
    enc[(size_t)(n * SRC + s) * 1024 + z * HE + j] = h;
}

// Decoder GRU step. grid (16,4), block 256 = 8n x 32j
__global__ __launch_bounds__(256) void dec_step_kernel(
    const float* __restrict__ gi, const float* __restrict__ WhhT,
    const float* __restrict__ bhh, const float* __restrict__ hin,
    float* __restrict__ hout, int t) {
    __shared__ float sh[8][HD];
    int tid = threadIdx.x;
    int n0 = blockIdx.y * 8;
    for (int i = tid; i < 8 * HD; i += 256)
        sh[i >> 9][i & 511] = hin[(size_t)(n0 + (i >> 9)) * HD + (i & 511)];
    __syncthreads();
    int j = blockIdx.x * 32 + (tid & 31);
    int nl = tid >> 5;
    int n = n0 + nl;
    float aR = bhh[j], aZ = bhh[HD + j], aN = bhh[2 * HD + j];
    for (int k = 0; k < HD; k += 4) {
        float4 h4 = *(const float4*)&sh[nl][k];
        const float* w0 = WhhT + (size_t)(k + 0) * G3;
        const float* w1 = WhhT + (size_t)(k + 1) * G3;
        const float* w2 = WhhT + (size_t)(k + 2) * G3;
        const float* w3 = WhhT + (size_t)(k + 3) * G3;
        aR += h4.x * w0[j] + h4.y * w1[j] + h4.z * w2[j] + h4.w * w3[j];
        aZ += h4.x * w0[HD + j] + h4.y * w1[HD + j] + h4.z * w2[HD + j] + h4.w * w3[HD + j];
        aN += h4.x * w0[2 * HD + j] + h4.y * w1[2 * HD + j] + h4.z * w2[2 * HD + j] + h4.w * w3[2 * HD + j];
    }
    const float* gir = gi + (size_t)(t * NB + n) * G3;
    float r  = sigmf(gir[j] + aR);
    float zz = sigmf(gir[HD + j] + aZ);
    float nn = tanhf(gir[2 * HD + j] + r * aN);
    float hp = sh[nl][j];
    hout[(size_t)n * HD + j] = (1.f - zz) * nn + zz * hp;
}

// key_proj: kp[(n*SRC+s)*512 + c] = sum_k enc[row][k]*Wk[k*512+c]. 8 rows/block.
__global__ __launch_bounds__(256) void keyproj_kernel(const float* __restrict__ enc,
                                                      const float* __restrict__ Wk,
                                                      float* __restrict__ kp) {
    __shared__ float sx[8][1024];
    int tid = threadIdx.x;
    int g0 = blockIdx.x * 8;
    for (int i = tid; i < 8 * 1024; i += 256)
        sx[i >> 10][i & 1023] = enc[(size_t)(g0 + (i >> 10)) * 1024 + (i & 1023)];
    __syncthreads();
    int c = blockIdx.y * 256 + tid;
    float acc[8];
#pragma unroll
    for (int r = 0; r < 8; ++r) acc[r] = 0.f;
    for (int k = 0; k < 1024; k += 4) {
        float w0 = Wk[(size_t)(k + 0) * 512 + c];
        float w1 = Wk[(size_t)(k + 1) * 512 + c];
        float w2 = Wk[(size_t)(k + 2) * 512 + c];
        float w3 = Wk[(size_t)(k + 3) * 512 + c];
#pragma unroll
        for (int r = 0; r < 8; ++r) {
            float4 x4 = *(const float4*)&sx[r][k];
            acc[r] += x4.x * w0 + x4.y * w1 + x4.z * w2 + x4.w * w3;
        }
    }
#pragma unroll
    for (int r = 0; r < 8; ++r) kp[(size_t)(g0 + r) * 512 + c] = acc[r];
}

// q[n][j] = battn[j] + sum_k h[n][k]*Wd[k*512+j]; block per n
__global__ __launch_bounds__(256) void q_kernel(const float* __restrict__ h,
                                                const float* __restrict__ Wd,
                                                const float* __restrict__ battn,
                                                float* __restrict__ q) {
    __shared__ float shh[512];
    int n = blockIdx.x, tid = threadIdx.x;
    shh[tid] = h[(size_t)n * 512 + tid];
    shh[256 + tid] = h[(size_t)n * 512 + 256 + tid];
    __syncthreads();
    float a0 = battn[tid], a1 = battn[256 + tid];
    for (int k = 0; k < 512; k += 4) {
        float4 h4 = *(const float4*)&shh[k];
        a0 += h4.x * Wd[(size_t)k * 512 + tid] + h4.y * Wd[(size_t)(k + 1) * 512 + tid]
            + h4.z * Wd[(size_t)(k + 2) * 512 + tid] + h4.w * Wd[(size_t)(k + 3) * 512 + tid];
        a1 += h4.x * Wd[(size_t)k * 512 + 256 + tid] + h4.y * Wd[(size_t)(k + 1) * 512 + 256 + tid]
            + h4.z * Wd[(size_t)(k + 2) * 512 + 256 + tid] + h4.w * Wd[(size_t)(k + 3) * 512 + 256 + tid];
    }
    q[(size_t)n * 512 + tid] = a0;
    q[(size_t)n * 512 + 256 + tid] = a1;
}

// e[row] = v . tanh(kp[row] + q[n]) + (1-mask)*PAD_INF ; one wave per row, 4 rows/block
__global__ __launch_bounds__(256) void escore_kernel(const float* __restrict__ kp,
                                                     const float* __restrict__ q,
                                                     const float* __restrict__ vvec,
                                                     const float* __restrict__ mask,
                                                     float* __restrict__ e) {
    __shared__ float sq[512];
    int tid = threadIdx.x;
    int row0 = blockIdx.x * 4;
    int n = row0 / SRC;   // 4 | SRC so all 4 rows share n
    sq[tid] = q[(size_t)n * 512 + tid];
    sq[256 + tid] = q[(size_t)n * 512 + 256 + tid];
    __syncthreads();
    int w = tid >> 6, lane = tid & 63;
    int row = row0 + w;
    int s = row % SRC;
    const float* kpr = kp + (size_t)row * 512;
    float acc = 0.f;
#pragma unroll
    for (int i = 0; i < 8; ++i) {
        int d = lane + i * 64;
        acc += vvec[d] * tanhf(kpr[d] + sq[d]);
    }
    for (int off = 32; off; off >>= 1) acc += __shfl_down(acc, off, 64);
    if (lane == 0) e[row] = acc + (1.f - mask[n * SRC + s]) * (-1e10f);
}

// softmax over S per n, in place. block per n.
__global__ __launch_bounds__(256) void softmaxS_kernel(float* __restrict__ e) {
    __shared__ float red[256];
    int n = blockIdx.x, tid = threadIdx.x;
    float* row = e + (size_t)n * SRC;
    float m = -3.4e38f;
    for (int s = tid; s < SRC; s += 256) m = fmaxf(m, row[s]);
    red[tid] = m; __syncthreads();
    for (int off = 128; off; off >>= 1) { if (tid < off) red[tid] = fmaxf(red[tid], red[tid + off]); __syncthreads(); }
    m = red[0]; __syncthreads();
    float sum = 0.f;
    for (int s = tid; s < SRC; s += 256) sum += expf(row[s] - m);
    red[tid] = sum; __syncthreads();
    for (int off = 128; off; off >>= 1) { if (tid < off) red[tid] += red[tid + off]; __syncthreads(); }
    float inv = 1.f / red[0]; __syncthreads();
    for (int s = tid; s < SRC; s += 256) row[s] = expf(row[s] - m) * inv;
}

// ctx[n][d] = sum_s attn[n][s]*enc[n][s][d]; grid (32 n, 4 dchunks)
__global__ __launch_bounds__(256) void ctx_kernel(const float* __restrict__ attn,
                                                  const float* __restrict__ enc,
                                                  float* __restrict__ ctx) {
    __shared__ float sa[SRC];
    int n = blockIdx.x, tid = threadIdx.x;
    for (int s = tid; s < SRC; s += 256) sa[s] = attn[n * SRC + s];
    __syncthreads();
    int d = blockIdx.y * 256 + tid;
    const float* er = enc + (size_t)n * SRC * 1024 + d;
    float acc = 0.f;
    for (int s = 0; s < SRC; ++s) acc += sa[s] * er[(size_t)s * 1024];
    ctx[(size_t)n * 1024 + d] = acc;
}

// p_gen[n] = sigmoid([xi, ctx, h] . Wp + bp); block per n
__global__ __launch_bounds__(256) void pgen_kernel(const int* __restrict__ trg_ids,
                                                   const float* __restrict__ embed,
                                                   const float* __restrict__ ctx,
                                                   const float* __restrict__ h,
                                                   const float* __restrict__ Wp,
                                                   const float* __restrict__ bp,
                                                   float* __restrict__ pgen, int t) {
    __shared__ float red[256];
    int n = blockIdx.x, tid = threadIdx.x;
    int tok = trg_ids[n * TDD + t];
    float acc = 0.f;
    for (int i = tid; i < 1792; i += 256) {
        float val;
        if (i < 256) val = embed[(size_t)tok * EMB + i];
        else if (i < 1280) val = ctx[(size_t)n * 1024 + (i - 256)];
        else val = h[(size_t)n * 512 + (i - 1280)];
        acc += val * Wp[i];
    }
    red[tid] = acc; __syncthreads();
    for (int off = 128; off; off >>= 1) { if (tid < off) red[tid] += red[tid + off]; __syncthreads(); }
    if (tid == 0) pgen[n] = 1.f / (1.f + expf(-(red[0] + bp[0])));
}

// hid1[n][j] = b1[j] + [h,ctx] . W1[:,j]; block per n
__global__ __launch_bounds__(256) void hid1_kernel(const float* __restrict__ h,
                                                   const float* __restrict__ ctx,
                                                   const float* __restrict__ W1,
                                                   const float* __restrict__ b1,
                                                   float* __restrict__ hid1) {
    __shared__ float sc[1536];
    int n = blockIdx.x, tid = threadIdx.x;
    for (int i = tid; i < 512; i += 256) sc[i] = h[(size_t)n * 512 + i];
    for (int i = tid; i < 1024; i += 256) sc[512 + i] = ctx[(size_t)n * 1024 + i];
    __syncthreads();
    float a0 = b1[tid], a1 = b1[256 + tid];
    for (int k = 0; k < 1536; k += 4) {
        float4 c4 = *(const float4*)&sc[k];
        a0 += c4.x * W1[(size_t)k * 512 + tid] + c4.y * W1[(size_t)(k + 1) * 512 + tid]
            + c4.z * W1[(size_t)(k + 2) * 512 + tid] + c4.w * W1[(size_t)(k + 3) * 512 + tid];
        a1 += c4.x * W1[(size_t)k * 512 + 256 + tid] + c4.y * W1[(size_t)(k + 1) * 512 + 256 + tid]
            + c4.z * W1[(size_t)(k + 2) * 512 + 256 + tid] + c4.w * W1[(size_t)(k + 3) * 512 + 256 + tid];
    }
    hid1[(size_t)n * 512 + tid] = a0;
    hid1[(size_t)n * 512 + 256 + tid] = a1;
}

// logits[n][j] = b2[j] + hid1[n] . W2[:,j]; thread per j, all 32 n in registers
__global__ __launch_bounds__(256) void logits_kernel(const float* __restrict__ hid1,
                                                     const float* __restrict__ W2,
                                                     const float* __restrict__ b2,
                                                     float* __restrict__ logits) {
    __shared__ float sh[NB][512];   // 64 KB
    int tid = threadIdx.x;
    for (int i = tid; i < NB * 512; i += 256) sh[i >> 9][i & 511] = hid1[i];
    __syncthreads();
    int j = blockIdx.x * 256 + tid;
    if (j >= VSZ) return;
    float acc[NB];
#pragma unroll
    for (int n = 0; n < NB; ++n) acc[n] = 0.f;
    for (int k = 0; k < 512; k += 4) {
        float w0 = W2[(size_t)(k + 0) * VSZ + j];
        float w1 = W2[(size_t)(k + 1) * VSZ + j];
        float w2 = W2[(size_t)(k + 2) * VSZ + j];
        float w3 = W2[(size_t)(k + 3) * VSZ + j];
#pragma unroll
        for (int n = 0; n < NB; ++n) {
            float4 h4 = *(const float4*)&sh[n][k];
            acc[n] += h4.x * w0 + h4.y * w1 + h4.z * w2 + h4.w * w3;
        }
    }
    float bb = b2[j];
#pragma unroll
    for (int n = 0; n < NB; ++n) logits[(size_t)n * VSZ + j] = acc[n] + bb;
}

// softmax over V, scale by p_gen, write out row (incl. zero OOV tail); block per n
__global__ __launch_bounds__(1024) void out_kernel(const float* __restrict__ logits,
                                                   const float* __restrict__ pgen,
                                                   float* __restrict__ out, int t) {
    __shared__ float red[1024];
    int n = blockIdx.x, tid = threadIdx.x;
    const float* lrow = logits + (size_t)n * VSZ;
    float m = -3.4e38f;
    for (int j = tid; j < VSZ; j += 1024) m = fmaxf(m, lrow[j]);
    red[tid] = m; __syncthreads();
    for (int off = 512; off; off >>= 1) { if (tid < off) red[tid] = fmaxf(red[tid], red[tid + off]); __syncthreads(); }
    m = red[0]; __syncthreads();
    float sum = 0.f;
    for (int j = tid; j < VSZ; j += 1024) sum += expf(lrow[j] - m);
    red[tid] = sum; __syncthreads();
    for (int off = 512; off; off >>= 1) { if (tid < off) red[tid] += red[tid + off]; __syncthreads(); }
    float inv = pgen[n] / red[0];
    float* orow = out + (size_t)(n * TDD + t) * VE;
    for (int j = tid; j < VE; j += 1024) orow[j] = (j < VSZ) ? expf(lrow[j] - m) * inv : 0.f;
}

// out[n, ptr[n,s]] += (1-p_gen[n]) * attn[n,s]
__global__ __launch_bounds__(256) void scatter_kernel(const int* __restrict__ ptr,
                                                      const float* __restrict__ attn,
                                                      const float* __restrict__ pgen,
                                                      float* __restrict__ out, int t) {
    int f = blockIdx.x * 256 + threadIdx.x;
    if (f >= NB * SRC) return;
    int n = f / SRC;
    float w = (1.f - pgen[n]) * attn[f];
    atomicAdd(&out[(size_t)(n * TDD + t) * VE + ptr[f]], w);
}

extern "C" void kernel_launch(void* const* d_in, const int* in_sizes, int n_in,
                              void* d_out, int out_size, void* d_ws, size_t ws_size,
                              hipStream_t stream) {
    const int*   src_ids  = (const int*)d_in[0];
    const float* src_mask = (const float*)d_in[1];
    const int*   trg_ids  = (const int*)d_in[2];
    const int*   ptr_idx  = (const int*)d_in[3];
    const float* embed    = (const float*)d_in[4];
    const float* Wih_f = (const float*)d_in[5];
    const float* Whh_f = (const float*)d_in[6];
    const float* bih_f = (const float*)d_in[7];
    const float* bhh_f = (const float*)d_in[8];
    const float* Wih_b = (const float*)d_in[9];
    const float* Whh_b = (const float*)d_in[10];
    const float* bih_b = (const float*)d_in[11];
    const float* bhh_b = (const float*)d_in[12];
    const float* Wih_d = (const float*)d_in[13];
    const float* Whh_d = (const float*)d_in[14];
    const float* bih_d = (const float*)d_in[15];
    const float* bhh_d = (const float*)d_in[16];
    const float* Wk    = (const float*)d_in[17];
    const float* Wd    = (const float*)d_in[18];
    const float* battn = (const float*)d_in[19];
    const float* vvec  = (const float*)d_in[20];
    const float* W1    = (const float*)d_in[21];
    const float* b1    = (const float*)d_in[22];
    const float* W2    = (const float*)d_in[23];
    const float* b2    = (const float*)d_in[24];
    const float* Wp    = (const float*)d_in[25];
    const float* bp    = (const float*)d_in[26];
    float* out = (float*)d_out;

    float* w = (float*)d_ws;
    float* WihTf = w; w += 256 * G3;
    float* WihTb = w; w += 256 * G3;
    float* WihTd = w; w += 256 * G3;
    float* WhhTf = w; w += 512 * G3;
    float* WhhTb = w; w += 512 * G3;
    float* WhhTd = w; w += 512 * G3;
    float* giF = w; w += (size_t)SRC * NB * G3;
    float* giB = w; w += (size_t)SRC * NB * G3;
    float* giD = w; w += (size_t)TDD * NB * G3;
    float* enc = w; w += (size_t)NB * SRC * 1024;
    float* kp  = w; w += (size_t)NB * SRC * 512;
    float* hF[2]; hF[0] = w; w += NB * HE; hF[1] = w; w += NB * HE;
    float* hB[2]; hB[0] = w; w += NB * HE; hB[1] = w; w += NB * HE;
    float* hDbuf[2]; hDbuf[0] = w; w += NB * HD; hDbuf[1] = w; w += NB * HD;
    float* q    = w; w += NB * 512;
    float* attn = w; w += NB * SRC;
    float* ctx  = w; w += NB * 1024;
    float* hid1 = w; w += NB * 512;
    float* pgen = w; w += 64;
    float* logits = w; w += (size_t)NB * VSZ;

    // ---- weight transposes ----
    transpose_kernel<<<(G3 * 256 + 255) / 256, 256, 0, stream>>>(Wih_f, WihTf, G3, 256);
    transpose_kernel<<<(G3 * 256 + 255) / 256, 256, 0, stream>>>(Wih_b, WihTb, G3, 256);
    transpose_kernel<<<(G3 * 256 + 255) / 256, 256, 0, stream>>>(Wih_d, WihTd, G3, 256);
    transpose_kernel<<<(G3 * 512 + 255) / 256, 256, 0, stream>>>(Whh_f, WhhTf, G3, 512);
    transpose_kernel<<<(G3 * 512 + 255) / 256, 256, 0, stream>>>(Whh_b, WhhTb, G3, 512);
    transpose_kernel<<<(G3 * 512 + 255) / 256, 256, 0, stream>>>(Whh_d, WhhTd, G3, 512);

    // ---- input-gate precompute ----
    gi_kernel<<<dim3(SRC * NB / 16, 6), 256, 0, stream>>>(src_ids, embed, WihTf, bih_f, giF, SRC);
    gi_kernel<<<dim3(SRC * NB / 16, 6), 256, 0, stream>>>(src_ids, embed, WihTb, bih_b, giB, SRC);
    gi_kernel<<<dim3(TDD * NB / 16, 6), 256, 0, stream>>>(trg_ids, embed, WihTd, bih_d, giD, TDD);

    hipMemsetAsync(hF[0], 0, NB * HE * sizeof(float), stream);
    hipMemsetAsync(hB[0], 0, NB * HE * sizeof(float), stream);
    hipMemsetAsync(hDbuf[0], 0, NB * HD * sizeof(float), stream);

    // ---- encoder scan (both directions per launch) ----
    for (int t = 0; t < SRC; ++t) {
        enc_step_kernel<<<dim3(16, 4, 2), 256, 0, stream>>>(
            giF, giB, WhhTf, WhhTb, bhh_f, bhh_b,
            hF[t & 1], hF[(t + 1) & 1], hB[t & 1], hB[(t + 1) & 1], enc, t);
    }

    keyproj_kernel<<<dim3(NB * SRC / 8, 2), 256, 0, stream>>>(enc, Wk, kp);

    // ---- decoder ----
    for (int t = 0; t < TDD; ++t) {
        const float* hi = hDbuf[t & 1];
        float* ho = hDbuf[(t + 1) & 1];
        dec_step_kernel<<<dim3(16, 4), 256, 0, stream>>>(giD, WhhTd, bhh_d, hi, ho, t);
        q_kernel<<<NB, 256, 0, stream>>>(ho, Wd, battn, q);
        escore_kernel<<<NB * SRC / 4, 256, 0, stream>>>(kp, q, vvec, src_mask, attn);
        softmaxS_kernel<<<NB, 256, 0, stream>>>(attn);
        ctx_kernel<<<dim3(NB, 4), 256, 0, stream>>>(attn, enc, ctx);
        pgen_kernel<<<NB, 256, 0, stream>>>(trg_ids, embed, ctx, ho, Wp, bp, pgen, t);
        hid1_kernel<<<NB, 256, 0, stream>>>(ho, ctx, W1, b1, hid1);
        logits_kernel<<<(VSZ + 255) / 256, 256, 0, stream>>>(hid1, W2, b2, logits);
        out_kernel<<<NB, 1024, 0, stream>>>(logits, pgen, out, t);
        scatter_kernel<<<(NB * SRC + 255) / 256, 256, 0, stream>>>(ptr_idx, attn, pgen, out, t);
    }
}